// Round 1
// baseline (554.496 us; speedup 1.0000x reference)
//
#include <hip/hip_runtime.h>

// Single-pass Otsu-split loss:
//   f(i) = T2 - S(i)^2/i - (T-S(i))^2/(k-i)   -- s2 prefix cancels, so only
//   per-bin (count, sum) needed. Bins = monotone float-bit encoding >> 19
//   (8192 bins over all floats; ~4.4% relative width -> split error ~1e-4
//   near t*~0, far below the 1.2e-2 absmax threshold).

#define NBINS 8192
#define HIST_BLOCKS 512
#define HIST_THREADS 1024   // 64KB LDS/block -> 2 blocks/CU = 32 waves/CU
#define FIN_THREADS 256
#define BPT (NBINS / FIN_THREADS)  // 32 bins per finalize thread

struct Scalars {
  unsigned long long kcount;  // number of masked (positive) elements
  double T;                   // sum of positives
  double T2;                  // sum of squares of positives
};

__device__ __forceinline__ unsigned fenc(float f) {
  // monotone (ascending) encoding of float into uint
  unsigned u = __float_as_uint(f);
  return (u & 0x80000000u) ? ~u : (u | 0x80000000u);
}

__global__ __launch_bounds__(HIST_THREADS)
void k_hist(const float4* __restrict__ x4, const int4* __restrict__ m4, long n4,
            const float* __restrict__ x, const int* __restrict__ m, long n,
            Scalars* __restrict__ sc, unsigned* __restrict__ gcount,
            double* __restrict__ gsum) {
  __shared__ unsigned hc[NBINS];   // 32 KiB
  __shared__ float    hs[NBINS];   // 32 KiB  (total exactly 64 KiB)
  for (int b = threadIdx.x; b < NBINS; b += HIST_THREADS) { hc[b] = 0u; hs[b] = 0.0f; }
  __syncthreads();

  long tid = (long)blockIdx.x * HIST_THREADS + threadIdx.x;
  long stride = (long)gridDim.x * HIST_THREADS;
  unsigned long long cnt = 0;
  double s = 0.0, s2 = 0.0;

#define PROC(vx, mv)                                            \
  if (mv) {                                                     \
    float v = (vx);                                             \
    int b = (int)(fenc(v) >> 19);                               \
    atomicAdd(&hc[b], 1u);                                      \
    atomicAdd(&hs[b], v);                                       \
    cnt++; s += (double)v; s2 += (double)v * (double)v;         \
  }

  for (long i = tid; i < n4; i += stride) {
    float4 xv = x4[i];
    int4 mv = m4[i];
    PROC(xv.x, mv.x)
    PROC(xv.y, mv.y)
    PROC(xv.z, mv.z)
    PROC(xv.w, mv.w)
  }
  if (tid == 0) {  // tail (n not multiple of 4)
    for (long i = n4 * 4; i < n; i++) { PROC(x[i], m[i]) }
  }
#undef PROC

  // wave-level reduce of global totals, one atomic trio per wave
  for (int off = 32; off > 0; off >>= 1) {
    cnt += __shfl_down(cnt, off);
    s   += __shfl_down(s, off);
    s2  += __shfl_down(s2, off);
  }
  if ((threadIdx.x & 63) == 0) {
    atomicAdd(&sc->kcount, cnt);
    atomicAdd(&sc->T, s);
    atomicAdd(&sc->T2, s2);
  }

  // flush only nonzero bins (exp-binning -> only a few hundred nonzero)
  __syncthreads();
  for (int b = threadIdx.x; b < NBINS; b += HIST_THREADS) {
    unsigned c = hc[b];
    if (c) {
      atomicAdd(&gcount[b], c);
      atomicAdd(&gsum[b], (double)hs[b]);
    }
  }
}

__global__ __launch_bounds__(FIN_THREADS)
void k_final(const Scalars* __restrict__ sc, const unsigned* __restrict__ gcount,
             const double* __restrict__ gsum, float* __restrict__ out) {
  __shared__ double             pS[FIN_THREADS];
  __shared__ unsigned long long pC[FIN_THREADS];
  __shared__ double             rf[FIN_THREADS];
  __shared__ double             rS[FIN_THREADS];
  __shared__ unsigned long long rI[FIN_THREADS];
  int t = threadIdx.x;

  unsigned long long K = sc->kcount;
  double kd = (double)K;
  double T = sc->T, T2 = sc->T2;

  // per-thread local totals over BPT consecutive bins
  unsigned long long c = 0; double s = 0.0;
  for (int j = 0; j < BPT; j++) { int b = t * BPT + j; c += gcount[b]; s += gsum[b]; }
  pC[t] = c; pS[t] = s;
  __syncthreads();
  // exclusive prefix across thread-chunks (serial by t0; 256 iters, trivial)
  if (t == 0) {
    unsigned long long cc = 0; double acc = 0.0;
    for (int i = 0; i < FIN_THREADS; i++) {
      unsigned long long c0 = pC[i]; double s0 = pS[i];
      pC[i] = cc; pS[i] = acc;
      cc += c0; acc += s0;
    }
  }
  __syncthreads();

  // evaluate f at every bin boundary, track argmin
  unsigned long long Ci = pC[t]; double Si = pS[t];
  double bestf = 1.0e300, bestS = 0.0; unsigned long long bestI = 0;
  for (int j = 0; j < BPT; j++) {
    int b = t * BPT + j;
    Ci += gcount[b]; Si += gsum[b];
    if (Ci >= 1ull && Ci < K) {
      double di = (double)Ci;
      double d1 = Si, d2 = T - Si;
      double f = T2 - d1 * d1 / di - d2 * d2 / (kd - di);
      if (f < bestf) { bestf = f; bestS = Si; bestI = Ci; }
    }
  }
  rf[t] = bestf; rS[t] = bestS; rI[t] = bestI;
  __syncthreads();
  if (t == 0) {
    for (int i = 1; i < FIN_THREADS; i++)
      if (rf[i] < bestf) { bestf = rf[i]; bestS = rS[i]; bestI = rI[i]; }
    double result = 0.0;
    if (K >= 2ull && bestI >= 1ull) {
      double var_tot = (T2 - T * T / kd) / kd;
      double reg = bestf / var_tot / kd;
      double pos_mean = bestS / (double)bestI;
      result = pos_mean + 0.5 * reg;
    }
    out[0] = (float)result;
  }
}

extern "C" void kernel_launch(void* const* d_in, const int* in_sizes, int n_in,
                              void* d_out, int out_size, void* d_ws, size_t ws_size,
                              hipStream_t stream) {
  const float* x = (const float*)d_in[0];
  const int* m = (const int*)d_in[1];
  long n = (long)in_sizes[0];
  long n4 = n >> 2;

  char* ws = (char*)d_ws;
  Scalars* sc = (Scalars*)ws;
  unsigned* gcount = (unsigned*)(ws + 64);
  double* gsum = (double*)(ws + 64 + NBINS * sizeof(unsigned));  // 8-aligned (32832)
  size_t used = 64 + NBINS * sizeof(unsigned) + NBINS * sizeof(double);

  hipMemsetAsync(d_ws, 0, used, stream);  // ws is re-poisoned 0xAA each call
  k_hist<<<HIST_BLOCKS, HIST_THREADS, 0, stream>>>(
      (const float4*)x, (const int4*)m, n4, x, m, n, sc, gcount, gsum);
  k_final<<<1, FIN_THREADS, 0, stream>>>(sc, gcount, gsum, (float*)d_out);
}